// Round 8
// baseline (199.083 us; speedup 1.0000x reference)
//
#include <hip/hip_runtime.h>
#include <hip/hip_bf16.h>

#define BATCH  4096
#define UNITS  1024
#define CDIM   2048   // K = UNITS + IN_DIM
#define NDIM   4096   // 4 * UNITS (f, i, c, o)

typedef __attribute__((ext_vector_type(8))) short bf16x8;
typedef __attribute__((ext_vector_type(4))) short bf16x4;
typedef __attribute__((ext_vector_type(4))) float f32x4;

__device__ __forceinline__ void gload_lds16(const void* g, void* l) {
    __builtin_amdgcn_global_load_lds(
        (const __attribute__((address_space(1))) unsigned int*)g,
        (__attribute__((address_space(3))) unsigned int*)l, 16, 0, 0);
}

__device__ __forceinline__ float sigm(float x) { return 1.f / (1.f + __expf(-x)); }
__device__ __forceinline__ float tanh_fast(float x) { return 2.f / (1.f + __expf(-2.f * x)) - 1.f; }

__device__ __forceinline__ short f2bf(float f) {
    __hip_bfloat16 h = __float2bfloat16(f);
    return *reinterpret_cast<short*>(&h);
}

// ---- prep v3 (FROZEN control: ~30 us, near 128 MB roofline) -----------------
// Wt row layout (gate-interleaved, 128-periodic):
//   n(u,g) = (u>>5)*128 + ((u>>4)&1)*64 + g*16 + (u&15)
__global__ __launch_bounds__(256) void prep(
        const float* __restrict__ h, const float* __restrict__ in,
        const float* __restrict__ Wf, const float* __restrict__ Wi,
        const float* __restrict__ Wc, const float* __restrict__ Wo,
        __hip_bfloat16* __restrict__ x, __hip_bfloat16* __restrict__ Wt) {
    __shared__ float lds[64 * 65];
    int b = blockIdx.x, tid = threadIdx.x;
    if (b < 4096) {
        int t   = b * 256 + tid;
        int row = t >> 8;
        int c8  = (t & 255) << 3;
        const float* src = (c8 < UNITS) ? (h + (size_t)row * UNITS + c8)
                                        : (in + (size_t)row * UNITS + (c8 - UNITS));
        float4 v0 = ((const float4*)src)[0];
        float4 v1 = ((const float4*)src)[1];
        bf16x8 o;
        o[0] = f2bf(v0.x); o[1] = f2bf(v0.y); o[2] = f2bf(v0.z); o[3] = f2bf(v0.w);
        o[4] = f2bf(v1.x); o[5] = f2bf(v1.y); o[6] = f2bf(v1.z); o[7] = f2bf(v1.w);
        *(bf16x8*)(x + (size_t)row * CDIM + c8) = o;
    } else {
        int idx = b - 4096;               // 2048 blocks = g(4) x kt(32) x ut(16)
        int g = idx >> 9, kt = (idx >> 4) & 31, ut = idx & 15;
        const float* W = (g == 0) ? Wf : (g == 1) ? Wi : (g == 2) ? Wc : Wo;
        int k0 = kt * 64, u0 = ut * 64;
        int r16 = tid & 15, hi = tid >> 4;
#pragma unroll
        for (int it = 0; it < 4; ++it) {
            int kl = it * 16 + hi;
            float4 v = *(const float4*)&W[(size_t)(k0 + kl) * UNITS + u0 + r16 * 4];
            float* d = &lds[kl * 65 + r16 * 4];
            d[0] = v.x; d[1] = v.y; d[2] = v.z; d[3] = v.w;
        }
        __syncthreads();
#pragma unroll
        for (int it = 0; it < 4; ++it) {
            int ul = it * 16 + hi;
            int u  = u0 + ul;
            int n  = ((u >> 5) << 7) + (((u >> 4) & 1) << 6) + (g << 4) + (u & 15);
            bf16x4 o;
#pragma unroll
            for (int j = 0; j < 4; ++j) o[j] = f2bf(lds[(r16 * 4 + j) * 65 + ul]);
            *(bf16x4*)(Wt + (size_t)n * CDIM + k0 + r16 * 4) = o;
        }
    }
}

// ---- gemm v6: 8-phase asm-LDS (R7 engine) + deep stage slots ----------------
// Change vs R7 (one variable): stage-slot map re-derived for max prefetch
// depth; vmcnt(4) (2 stage-groups in flight) instead of vmcnt(2).
// Region-free rule: a buffer is staged only in a phase STRICTLY AFTER its
// last ds_read phase (barrier between) -> no DMA/ds_read race.
//   last reads: A[p0]h0@P3, A[p0]h1@P4, B[p0]@P3, A[p1]h0@P7, A[p1]h1@P8,
//               B[p1]@P7   (h of A = wm-half; IH0 phases read A rows 0-63,
//               IH1 rows 64-127; B read fully at every IH0 phase)
// Slots: P1:A[p1,h0](t1)  P2:A[p1,h1](t1)  P4:B[p0,h0]+B[p0,h1](t2)
//        P5:A[p0,h0](t2)  P6:A[p0,h1](t2)  P8:B[p1,h0]+B[p1,h1](t3)
// Waits: end-P4 vmcnt(4): outstanding {P8prev:4,P1:2,P2:2,P4:4}=12 ->
//        retires all p1(t1) (coverage 2.3-4.5 phases) before P5 reads.
//        end-P8 vmcnt(4): {P4:4,P5:2,P6:2,P8:4}=12 -> retires p0(t2)
//        (coverage 2.3-4.5 phases) before next P1 reads.
// LDS map (bytes): A[p][h] @ (p*2+h)*16384 ; B[p][h] @ 65536+(p*2+h)*16384.
__global__ __launch_bounds__(512, 2) void gemm_lstm(
    const __hip_bfloat16* __restrict__ A,    // [BATCH, CDIM] bf16
    const __hip_bfloat16* __restrict__ Bt,   // [NDIM, CDIM] bf16, gate-interleaved
    const float* __restrict__ b_f, const float* __restrict__ b_i,
    const float* __restrict__ b_c, const float* __restrict__ b_o,
    const float* __restrict__ cell,          // [BATCH, UNITS]
    float* __restrict__ out)                 // [2, BATCH, UNITS]: hidden, cell
{
    extern __shared__ short smem[];          // 65536 shorts = 128 KB
    const int K = CDIM;

    int bid = blockIdx.x;
    int nb  = (bid & 7) * 2 + ((bid >> 3) & 1);   // 0..15 (XCD swizzle)
    int mb  = bid >> 4;                           // 0..15
    int m0  = mb * 256, n0 = nb * 256;

    int tid  = threadIdx.x;
    int w    = tid >> 6, lane = tid & 63;
    int wm   = w >> 2, wn2 = w & 3;
    int quad = lane >> 4, r16 = lane & 15;

    f32x4 acc[8][4];
#pragma unroll
    for (int i = 0; i < 8; ++i)
#pragma unroll
        for (int j = 0; j < 4; ++j) acc[i][j] = (f32x4){0.f, 0.f, 0.f, 0.f};

    const short* Ag0 = (const short*)A  + (size_t)(m0)       * K;
    const short* Ag1 = (const short*)A  + (size_t)(m0 + 128) * K;
    const short* Bg0 = (const short*)Bt + (size_t)(n0)       * K;
    const short* Bg1 = (const short*)Bt + (size_t)(n0 + 128) * K;

    short* lds = smem;
    unsigned SB  = (unsigned)(size_t)(__attribute__((address_space(3))) short*)smem;
    unsigned kc0 = (unsigned)((quad ^ (r16 & 7)) * 16);
    unsigned kc1 = (unsigned)(((quad + 4) ^ (r16 & 7)) * 16);
    unsigned aA  = SB + wm * 16384 + r16 * 128;           // + p*32768 + kc
    unsigned aB  = SB + 65536 + wn2 * 8192 + r16 * 128;   // + p*32768 + kc

    bf16x8 bfr[4];

#define STG(SRC, DSTOFF, KT)                                                   \
    { _Pragma("unroll")                                                        \
      for (int q_ = 0; q_ < 2; ++q_) {                                         \
          int s_ = q_ * 512 + tid;                                             \
          int row_ = s_ >> 3, cg_ = (s_ & 7) ^ (row_ & 7);                     \
          gload_lds16(SRC + (size_t)row_ * K + (KT) * 64 + cg_ * 8,            \
                      lds + (DSTOFF) + s_ * 8);                                \
      } }

#define DSR(DST, ADDR, OFFTXT)                                                 \
    asm volatile("ds_read_b128 %0, %1 " OFFTXT : "=v"(DST) : "v"(ADDR) : "memory");

#define PHASE(P, KS, IH, STAGE_CODE, WAIT_CODE)                                \
    {                                                                          \
        unsigned adA_ = aA + (P) * 32768 + ((KS) ? kc1 : kc0);                 \
        bf16x8 af0, af1, af2, af3;                                             \
        if ((IH) == 0) {                                                       \
            unsigned adB_ = aB + (P) * 32768 + ((KS) ? kc1 : kc0);             \
            DSR(af0, adA_, "")                                                 \
            DSR(af1, adA_, "offset:2048")                                      \
            DSR(af2, adA_, "offset:4096")                                      \
            DSR(af3, adA_, "offset:6144")                                      \
            DSR(bfr[0], adB_, "")                                              \
            DSR(bfr[1], adB_, "offset:2048")                                   \
            DSR(bfr[2], adB_, "offset:4096")                                   \
            DSR(bfr[3], adB_, "offset:6144")                                   \
        } else {                                                               \
            DSR(af0, adA_, "offset:8192")                                      \
            DSR(af1, adA_, "offset:10240")                                     \
            DSR(af2, adA_, "offset:12288")                                     \
            DSR(af3, adA_, "offset:14336")                                     \
        }                                                                      \
        STAGE_CODE;                                                            \
        asm volatile("s_barrier" ::: "memory");                                \
        asm volatile("s_waitcnt lgkmcnt(0)" ::: "memory");                     \
        __builtin_amdgcn_sched_barrier(0);                                     \
        __builtin_amdgcn_s_setprio(1);                                         \
        _Pragma("unroll")                                                      \
        for (int j_ = 0; j_ < 4; ++j_) {                                       \
            acc[(IH)*4+0][j_] = __builtin_amdgcn_mfma_f32_16x16x32_bf16(af0, bfr[j_], acc[(IH)*4+0][j_], 0, 0, 0); \
            acc[(IH)*4+1][j_] = __builtin_amdgcn_mfma_f32_16x16x32_bf16(af1, bfr[j_], acc[(IH)*4+1][j_], 0, 0, 0); \
            acc[(IH)*4+2][j_] = __builtin_amdgcn_mfma_f32_16x16x32_bf16(af2, bfr[j_], acc[(IH)*4+2][j_], 0, 0, 0); \
            acc[(IH)*4+3][j_] = __builtin_amdgcn_mfma_f32_16x16x32_bf16(af3, bfr[j_], acc[(IH)*4+3][j_], 0, 0, 0); \
        }                                                                      \
        __builtin_amdgcn_s_setprio(0);                                         \
        __builtin_amdgcn_sched_barrier(0);                                     \
        WAIT_CODE;                                                             \
        asm volatile("s_barrier" ::: "memory");                                \
    }

#define VM4 asm volatile("s_waitcnt vmcnt(4)" ::: "memory")
#define VM0 asm volatile("s_waitcnt vmcnt(0)" ::: "memory")
#define NOPX ((void)0)

    // Prologue: stage t0 -> p0 (all 4 halves) + B[p1,*](t1); retire t0 only.
    STG(Ag0, 0,     0)
    STG(Ag1, 8192,  0)
    STG(Bg0, 32768, 0)
    STG(Bg1, 40960, 0)
    STG(Bg0, 49152, 1)
    STG(Bg1, 57344, 1)
    VM4;                                   // t0 resident; B(t1) 4 loads in flight
    asm volatile("s_barrier" ::: "memory");

    for (int u = 0; u < 15; ++u) {
        int t1 = 2 * u + 1, t2 = 2 * u + 2, t3 = 2 * u + 3;
        PHASE(0, 0, 0, STG(Ag0, 16384, t1), NOPX)                          // P1
        PHASE(0, 0, 1, STG(Ag1, 24576, t1), NOPX)                          // P2
        PHASE(0, 1, 0, NOPX, NOPX)                                         // P3
        PHASE(0, 1, 1, STG(Bg0, 32768, t2) STG(Bg1, 40960, t2), VM4)       // P4
        PHASE(1, 0, 0, STG(Ag0, 0,     t2), NOPX)                          // P5
        PHASE(1, 0, 1, STG(Ag1, 8192,  t2), NOPX)                          // P6
        PHASE(1, 1, 0, NOPX, NOPX)                                         // P7
        PHASE(1, 1, 1, STG(Bg0, 49152, t3) STG(Bg1, 57344, t3), VM4)       // P8
    }
    // Tail u=15: t1=31 (p1), t2/t3 do not exist.
    PHASE(0, 0, 0, STG(Ag0, 16384, 31), NOPX)
    PHASE(0, 0, 1, STG(Ag1, 24576, 31), NOPX)
    PHASE(0, 1, 0, NOPX, NOPX)
    PHASE(0, 1, 1, NOPX, VM0)
    PHASE(1, 0, 0, NOPX, NOPX)
    PHASE(1, 0, 1, NOPX, NOPX)
    PHASE(1, 1, 0, NOPX, NOPX)
    PHASE(1, 1, 1, NOPX, NOPX)

#undef PHASE
#undef DSR
#undef STG
#undef VM4
#undef VM0
#undef NOPX

    // ---- fused LSTM epilogue (R0-proven mapping; j = gate) ------------------
    int uo = nb * 64 + (wn2 >> 1) * 32 + (wn2 & 1) * 16 + r16;
    float bfv = b_f[uo], biv = b_i[uo], bcv = b_c[uo], bov = b_o[uo];
    float* out_h = out;
    float* out_c = out + (size_t)BATCH * UNITS;
#pragma unroll
    for (int i = 0; i < 8; ++i) {
#pragma unroll
        for (int rr = 0; rr < 4; ++rr) {
            int m = m0 + wm * 128 + i * 16 + quad * 4 + rr;
            float fg = sigm(acc[i][0][rr] + bfv);
            float ig = sigm(acc[i][1][rr] + biv);
            float cc = tanh_fast(acc[i][2][rr] + bcv);
            float og = sigm(acc[i][3][rr] + bov);
            float cold = cell[(size_t)m * UNITS + uo];
            float cn = fg * cold + ig * cc;
            out_h[(size_t)m * UNITS + uo] = og * tanh_fast(cn);
            out_c[(size_t)m * UNITS + uo] = cn;
        }
    }
}

extern "C" void kernel_launch(void* const* d_in, const int* in_sizes, int n_in,
                              void* d_out, int out_size, void* d_ws, size_t ws_size,
                              hipStream_t stream) {
    const float* inputs = (const float*)d_in[0];
    const float* hidden = (const float*)d_in[1];
    const float* cell   = (const float*)d_in[2];
    const float* Wf = (const float*)d_in[3];
    const float* bf_ = (const float*)d_in[4];
    const float* Wi = (const float*)d_in[5];
    const float* bi_ = (const float*)d_in[6];
    const float* Wc = (const float*)d_in[7];
    const float* bc_ = (const float*)d_in[8];
    const float* Wo = (const float*)d_in[9];
    const float* bo_ = (const float*)d_in[10];
    float* out = (float*)d_out;

    char* ws = (char*)d_ws;
    __hip_bfloat16* x  = (__hip_bfloat16*)ws;                  // 16 MB
    __hip_bfloat16* Wt = (__hip_bfloat16*)(ws + (16u << 20));  // 16 MB

    static bool attr_set = false;
    if (!attr_set) {
        hipFuncSetAttribute(reinterpret_cast<const void*>(gemm_lstm),
                            hipFuncAttributeMaxDynamicSharedMemorySize, 131072);
        attr_set = true;
    }

    prep<<<dim3(6144), dim3(256), 0, stream>>>(hidden, inputs, Wf, Wi, Wc, Wo, x, Wt);
    gemm_lstm<<<dim3(256), dim3(512), 131072, stream>>>(
        x, Wt, bf_, bi_, bc_, bo_, cell, out);
}

// Round 9
// 198.476 us; speedup vs baseline: 1.0031x; 1.0031x over previous
//
#include <hip/hip_runtime.h>
#include <hip/hip_bf16.h>

#define BATCH  4096
#define UNITS  1024
#define CDIM   2048   // K = UNITS + IN_DIM
#define NDIM   4096   // 4 * UNITS (f, i, c, o)

typedef __attribute__((ext_vector_type(8))) short bf16x8;
typedef __attribute__((ext_vector_type(4))) short bf16x4;
typedef __attribute__((ext_vector_type(4))) float f32x4;

__device__ __forceinline__ void gload_lds16(const void* g, void* l) {
    __builtin_amdgcn_global_load_lds(
        (const __attribute__((address_space(1))) unsigned int*)g,
        (__attribute__((address_space(3))) unsigned int*)l, 16, 0, 0);
}

__device__ __forceinline__ float sigm(float x) { return 1.f / (1.f + __expf(-x)); }
__device__ __forceinline__ float tanh_fast(float x) { return 2.f / (1.f + __expf(-2.f * x)) - 1.f; }

__device__ __forceinline__ short f2bf(float f) {
    __hip_bfloat16 h = __float2bfloat16(f);
    return *reinterpret_cast<short*>(&h);
}

// ---- prep v3 (FROZEN control: ~30 us, near 128 MB roofline) -----------------
// Wt row layout (gate-interleaved, 128-periodic):
//   n(u,g) = (u>>5)*128 + ((u>>4)&1)*64 + g*16 + (u&15)
__global__ __launch_bounds__(256) void prep(
        const float* __restrict__ h, const float* __restrict__ in,
        const float* __restrict__ Wf, const float* __restrict__ Wi,
        const float* __restrict__ Wc, const float* __restrict__ Wo,
        __hip_bfloat16* __restrict__ x, __hip_bfloat16* __restrict__ Wt) {
    __shared__ float lds[64 * 65];
    int b = blockIdx.x, tid = threadIdx.x;
    if (b < 4096) {
        int t   = b * 256 + tid;
        int row = t >> 8;
        int c8  = (t & 255) << 3;
        const float* src = (c8 < UNITS) ? (h + (size_t)row * UNITS + c8)
                                        : (in + (size_t)row * UNITS + (c8 - UNITS));
        float4 v0 = ((const float4*)src)[0];
        float4 v1 = ((const float4*)src)[1];
        bf16x8 o;
        o[0] = f2bf(v0.x); o[1] = f2bf(v0.y); o[2] = f2bf(v0.z); o[3] = f2bf(v0.w);
        o[4] = f2bf(v1.x); o[5] = f2bf(v1.y); o[6] = f2bf(v1.z); o[7] = f2bf(v1.w);
        *(bf16x8*)(x + (size_t)row * CDIM + c8) = o;
    } else {
        int idx = b - 4096;               // 2048 blocks = g(4) x kt(32) x ut(16)
        int g = idx >> 9, kt = (idx >> 4) & 31, ut = idx & 15;
        const float* W = (g == 0) ? Wf : (g == 1) ? Wi : (g == 2) ? Wc : Wo;
        int k0 = kt * 64, u0 = ut * 64;
        int r16 = tid & 15, hi = tid >> 4;
#pragma unroll
        for (int it = 0; it < 4; ++it) {
            int kl = it * 16 + hi;
            float4 v = *(const float4*)&W[(size_t)(k0 + kl) * UNITS + u0 + r16 * 4];
            float* d = &lds[kl * 65 + r16 * 4];
            d[0] = v.x; d[1] = v.y; d[2] = v.z; d[3] = v.w;
        }
        __syncthreads();
#pragma unroll
        for (int it = 0; it < 4; ++it) {
            int ul = it * 16 + hi;
            int u  = u0 + ul;
            int n  = ((u >> 5) << 7) + (((u >> 4) & 1) << 6) + (g << 4) + (u & 15);
            bf16x4 o;
#pragma unroll
            for (int j = 0; j < 4; ++j) o[j] = f2bf(lds[(r16 * 4 + j) * 65 + ul]);
            *(bf16x4*)(Wt + (size_t)n * CDIM + k0 + r16 * 4) = o;
        }
    }
}

// ---- gemm v7: 8-phase asm-LDS + ONE-PHASE-AHEAD fragment pipeline -----------
// Change vs R8 (one variable): fragment ds_reads for phase i+1 are issued
// AFTER phase i's lgkmcnt(0), BEFORE phase i's MFMA cluster -> LDS read burst
// runs under the ~620-cyc matrix-pipe cluster instead of serializing with it.
// Register double-buffer: A frag sets X/Y alternate every phase; B sets M/N
// alternate every KS pair. Stage slots + vmcnt arithmetic unchanged from R8.
// Phase skeleton: {STAGE; [vmcnt]; s_barrier; lgkmcnt(0); SCHED;
//                  FRAG(i+1) issue; SCHED; setprio1 MFMA(i) setprio0; SCHED;
//                  s_barrier}
// Safety (re-derived for read-ahead):
//  WAR: stage(j) region disjoint from FRAG(j) AND FRAG(j+1) reads:
//   P1 A[p1,h0] vs p0,p0 OK | P2 A[p1,h1] vs p0,p0 OK | P4 B[p0] vs A[p0],p1
//   OK | P5 A[p0,h0] vs p1,p1 OK | P6 A[p0,h1] vs p1,p1 OK | P8 B[p1] vs
//   A[p1],p0 OK. A stage never at P8 (would race FRAG(P8) queued reads).
//  Read-validity: FRAG(P5) (reads p1=t1) issued after P4's vmcnt(4)+barrier
//   (retires P8prev B + P1/P2 A = t1 complete; outstanding 12->4).
//   FRAG(P1') (reads p0=t2) issued after P8's vmcnt(4)+barrier (retires
//   P4 B + P5/P6 A = t2 complete). Same counts as R8.
// LDS map (bytes): A[p][h] @ (p*2+h)*16384 ; B[p][h] @ 65536+(p*2+h)*16384.
__global__ __launch_bounds__(512, 2) void gemm_lstm(
    const __hip_bfloat16* __restrict__ A,    // [BATCH, CDIM] bf16
    const __hip_bfloat16* __restrict__ Bt,   // [NDIM, CDIM] bf16, gate-interleaved
    const float* __restrict__ b_f, const float* __restrict__ b_i,
    const float* __restrict__ b_c, const float* __restrict__ b_o,
    const float* __restrict__ cell,          // [BATCH, UNITS]
    float* __restrict__ out)                 // [2, BATCH, UNITS]: hidden, cell
{
    extern __shared__ short smem[];          // 65536 shorts = 128 KB
    const int K = CDIM;

    int bid = blockIdx.x;
    int nb  = (bid & 7) * 2 + ((bid >> 3) & 1);   // 0..15 (XCD swizzle)
    int mb  = bid >> 4;                           // 0..15
    int m0  = mb * 256, n0 = nb * 256;

    int tid  = threadIdx.x;
    int w    = tid >> 6, lane = tid & 63;
    int wm   = w >> 2, wn2 = w & 3;
    int quad = lane >> 4, r16 = lane & 15;

    f32x4 acc[8][4];
#pragma unroll
    for (int i = 0; i < 8; ++i)
#pragma unroll
        for (int j = 0; j < 4; ++j) acc[i][j] = (f32x4){0.f, 0.f, 0.f, 0.f};

    const short* Ag0 = (const short*)A  + (size_t)(m0)       * K;
    const short* Ag1 = (const short*)A  + (size_t)(m0 + 128) * K;
    const short* Bg0 = (const short*)Bt + (size_t)(n0)       * K;
    const short* Bg1 = (const short*)Bt + (size_t)(n0 + 128) * K;

    short* lds = smem;
    unsigned SB  = (unsigned)(size_t)(__attribute__((address_space(3))) short*)smem;
    unsigned kc0 = (unsigned)((quad ^ (r16 & 7)) * 16);
    unsigned kc1 = (unsigned)(((quad + 4) ^ (r16 & 7)) * 16);
    unsigned aA  = SB + wm * 16384 + r16 * 128;           // + p*32768 + kc
    unsigned aB  = SB + 65536 + wn2 * 8192 + r16 * 128;   // + p*32768 + kc

    // fragment double-buffers (register)
    bf16x8 afX0, afX1, afX2, afX3, afY0, afY1, afY2, afY3;
    bf16x8 bfM0, bfM1, bfM2, bfM3, bfN0, bfN1, bfN2, bfN3;

#define STG(SRC, DSTOFF, KT)                                                   \
    { _Pragma("unroll")                                                        \
      for (int q_ = 0; q_ < 2; ++q_) {                                         \
          int s_ = q_ * 512 + tid;                                             \
          int row_ = s_ >> 3, cg_ = (s_ & 7) ^ (row_ & 7);                     \
          gload_lds16(SRC + (size_t)row_ * K + (KT) * 64 + cg_ * 8,            \
                      lds + (DSTOFF) + s_ * 8);                                \
      } }

#define DSR(DST, ADDR, OFFTXT)                                                 \
    asm volatile("ds_read_b128 %0, %1 " OFFTXT : "=v"(DST) : "v"(ADDR) : "memory");

#define FRAGA0(S, PB, KC) { unsigned a_ = aA + (PB) * 32768 + (KC);            \
    DSR(af##S##0, a_, "")              DSR(af##S##1, a_, "offset:2048")        \
    DSR(af##S##2, a_, "offset:4096")   DSR(af##S##3, a_, "offset:6144") }
#define FRAGA1(S, PB, KC) { unsigned a_ = aA + (PB) * 32768 + (KC);            \
    DSR(af##S##0, a_, "offset:8192")   DSR(af##S##1, a_, "offset:10240")       \
    DSR(af##S##2, a_, "offset:12288")  DSR(af##S##3, a_, "offset:14336") }
#define FRAGB(S, PB, KC) { unsigned b_ = aB + (PB) * 32768 + (KC);             \
    DSR(bf##S##0, b_, "")              DSR(bf##S##1, b_, "offset:2048")        \
    DSR(bf##S##2, b_, "offset:4096")   DSR(bf##S##3, b_, "offset:6144") }

#define MFJ(UA, BREG, IH, J)                                                   \
    acc[(IH)*4+0][J] = __builtin_amdgcn_mfma_f32_16x16x32_bf16(af##UA##0, BREG, acc[(IH)*4+0][J], 0, 0, 0); \
    acc[(IH)*4+1][J] = __builtin_amdgcn_mfma_f32_16x16x32_bf16(af##UA##1, BREG, acc[(IH)*4+1][J], 0, 0, 0); \
    acc[(IH)*4+2][J] = __builtin_amdgcn_mfma_f32_16x16x32_bf16(af##UA##2, BREG, acc[(IH)*4+2][J], 0, 0, 0); \
    acc[(IH)*4+3][J] = __builtin_amdgcn_mfma_f32_16x16x32_bf16(af##UA##3, BREG, acc[(IH)*4+3][J], 0, 0, 0);

#define PHASE(UA, UB, IH, FRAGCODE, STAGECODE, WAITCODE)                       \
    {                                                                          \
        STAGECODE;                                                             \
        WAITCODE;                                                              \
        asm volatile("s_barrier" ::: "memory");                                \
        asm volatile("s_waitcnt lgkmcnt(0)" ::: "memory");                     \
        __builtin_amdgcn_sched_barrier(0);                                     \
        FRAGCODE;                                                              \
        __builtin_amdgcn_sched_barrier(0);                                     \
        __builtin_amdgcn_s_setprio(1);                                         \
        MFJ(UA, bf##UB##0, IH, 0)                                              \
        MFJ(UA, bf##UB##1, IH, 1)                                              \
        MFJ(UA, bf##UB##2, IH, 2)                                              \
        MFJ(UA, bf##UB##3, IH, 3)                                              \
        __builtin_amdgcn_s_setprio(0);                                         \
        __builtin_amdgcn_sched_barrier(0);                                     \
        asm volatile("s_barrier" ::: "memory");                                \
    }

#define VM4 asm volatile("s_waitcnt vmcnt(4)" ::: "memory")
#define VM0 asm volatile("s_waitcnt vmcnt(0)" ::: "memory")
#define NOPX ((void)0)

    // Prologue: stage t0 -> p0 (4 halves, 8 loads) + B[p1,*](t1, 4 loads);
    // vmcnt(4) retires t0; barrier; issue FRAG(P1) into {X, M}.
    STG(Ag0, 0,     0)
    STG(Ag1, 8192,  0)
    STG(Bg0, 32768, 0)
    STG(Bg1, 40960, 0)
    STG(Bg0, 49152, 1)
    STG(Bg1, 57344, 1)
    VM4;
    asm volatile("s_barrier" ::: "memory");
    FRAGA0(X, 0, kc0)
    FRAGB(M, 0, kc0)

    for (int u = 0; u < 15; ++u) {
        int t1 = 2 * u + 1, t2 = 2 * u + 2, t3 = 2 * u + 3;
        PHASE(X, M, 0, FRAGA1(Y, 0, kc0),                   STG(Ag0, 16384, t1), NOPX)                     // P1
        PHASE(Y, M, 1, FRAGA0(X, 0, kc1) FRAGB(N, 0, kc1),  STG(Ag1, 24576, t1), NOPX)                     // P2
        PHASE(X, N, 0, FRAGA1(Y, 0, kc1),                   NOPX, NOPX)                                    // P3
        PHASE(Y, N, 1, FRAGA0(X, 1, kc0) FRAGB(M, 1, kc0),  STG(Bg0, 32768, t2) STG(Bg1, 40960, t2), VM4)  // P4
        PHASE(X, M, 0, FRAGA1(Y, 1, kc0),                   STG(Ag0, 0,     t2), NOPX)                     // P5
        PHASE(Y, M, 1, FRAGA0(X, 1, kc1) FRAGB(N, 1, kc1),  STG(Ag1, 8192,  t2), NOPX)                     // P6
        PHASE(X, N, 0, FRAGA1(Y, 1, kc1),                   NOPX, NOPX)                                    // P7
        PHASE(Y, N, 1, FRAGA0(X, 0, kc0) FRAGB(M, 0, kc0),  STG(Bg0, 49152, t3) STG(Bg1, 57344, t3), VM4)  // P8
    }
    // Tail u=15: t1=31 (p1); t2/t3 absent. vmcnt(0) at P4 (only 8 outstanding).
    PHASE(X, M, 0, FRAGA1(Y, 0, kc0),                   STG(Ag0, 16384, 31), NOPX)
    PHASE(Y, M, 1, FRAGA0(X, 0, kc1) FRAGB(N, 0, kc1),  STG(Ag1, 24576, 31), NOPX)
    PHASE(X, N, 0, FRAGA1(Y, 0, kc1),                   NOPX, NOPX)
    PHASE(Y, N, 1, FRAGA0(X, 1, kc0) FRAGB(M, 1, kc0),  NOPX, VM0)
    PHASE(X, M, 0, FRAGA1(Y, 1, kc0),                   NOPX, NOPX)
    PHASE(Y, M, 1, FRAGA0(X, 1, kc1) FRAGB(N, 1, kc1),  NOPX, NOPX)
    PHASE(X, N, 0, FRAGA1(Y, 1, kc1),                   NOPX, NOPX)
    PHASE(Y, N, 1, NOPX,                                NOPX, NOPX)

#undef PHASE
#undef MFJ
#undef FRAGA0
#undef FRAGA1
#undef FRAGB
#undef DSR
#undef STG
#undef VM4
#undef VM0
#undef NOPX

    // ---- fused LSTM epilogue (R0-proven mapping; j = gate) ------------------
    int uo = nb * 64 + (wn2 >> 1) * 32 + (wn2 & 1) * 16 + r16;
    float bfv = b_f[uo], biv = b_i[uo], bcv = b_c[uo], bov = b_o[uo];
    float* out_h = out;
    float* out_c = out + (size_t)BATCH * UNITS;
#pragma unroll
    for (int i = 0; i < 8; ++i) {
#pragma unroll
        for (int rr = 0; rr < 4; ++rr) {
            int m = m0 + wm * 128 + i * 16 + quad * 4 + rr;
            float fg = sigm(acc[i][0][rr] + bfv);
            float ig = sigm(acc[i][1][rr] + biv);
            float cc = tanh_fast(acc[i][2][rr] + bcv);
            float og = sigm(acc[i][3][rr] + bov);
            float cold = cell[(size_t)m * UNITS + uo];
            float cn = fg * cold + ig * cc;
            out_h[(size_t)m * UNITS + uo] = og * tanh_fast(cn);
            out_c[(size_t)m * UNITS + uo] = cn;
        }
    }
}

extern "C" void kernel_launch(void* const* d_in, const int* in_sizes, int n_in,
                              void* d_out, int out_size, void* d_ws, size_t ws_size,
                              hipStream_t stream) {
    const float* inputs = (const float*)d_in[0];
    const float* hidden = (const float*)d_in[1];
    const float* cell   = (const float*)d_in[2];
    const float* Wf = (const float*)d_in[3];
    const float* bf_ = (const float*)d_in[4];
    const float* Wi = (const float*)d_in[5];
    const float* bi_ = (const float*)d_in[6];
    const float* Wc = (const float*)d_in[7];
    const float* bc_ = (const float*)d_in[8];
    const float* Wo = (const float*)d_in[9];
    const float* bo_ = (const float*)d_in[10];
    float* out = (float*)d_out;

    char* ws = (char*)d_ws;
    __hip_bfloat16* x  = (__hip_bfloat16*)ws;                  // 16 MB
    __hip_bfloat16* Wt = (__hip_bfloat16*)(ws + (16u << 20));  // 16 MB

    static bool attr_set = false;
    if (!attr_set) {
        hipFuncSetAttribute(reinterpret_cast<const void*>(gemm_lstm),
                            hipFuncAttributeMaxDynamicSharedMemorySize, 131072);
        attr_set = true;
    }

    prep<<<dim3(6144), dim3(256), 0, stream>>>(hidden, inputs, Wf, Wi, Wc, Wo, x, Wt);
    gemm_lstm<<<dim3(256), dim3(512), 131072, stream>>>(
        x, Wt, bf_, bi_, bc_, bo_, cell, out);
}